// Round 12
// baseline (160.246 us; speedup 1.0000x reference)
//
#include <hip/hip_runtime.h>

#define HEADS 8
#define HDIM 32
#define NTOK 1024
#define CDIM 256
#define BATCH 16
#define ATT_SCALE 0.17677669529663687f  // 32^-0.5
#define L2E 1.4426950408889634f
#define BSTR 1544   // bias copy stride (floats): 16B-aligned; 1544%32=8 -> ~2-way reads
#define XSTR 514    // qkv LDS x-tile row stride (f32): even (8B align) and 514%32=2
                    // -> column fragment reads land 2 lanes/bank = conflict-free

typedef __attribute__((ext_vector_type(8))) short bf16x8;   // 8 bf16, 4 VGPRs
typedef __attribute__((ext_vector_type(4))) float f32x4;    // MFMA C/D

__device__ __forceinline__ unsigned short f2bf(float f) {
    unsigned int u = __float_as_uint(f);
    return (unsigned short)((u + 0x7fffu + ((u >> 16) & 1u)) >> 16);  // RNE
}

// pack two f32 -> (bf16(lo) | bf16(hi)<<16) in one instruction; RNE == f2bf
__device__ __forceinline__ unsigned cvt_pk_bf16(float lo, float hi) {
    unsigned r;
    asm("v_cvt_pk_bf16_f32 %0, %1, %2" : "=v"(r) : "v"(lo), "v"(hi));
    return r;
}

// ---------------------------------------------------------------------------
// Weight prep only: fp32 -> bf16, Wk pre-scaled by ATT_SCALE*log2(e).
// ---------------------------------------------------------------------------
__global__ __launch_bounds__(256) void prepw_kernel(
    const float* __restrict__ Wq, const float* __restrict__ Wk,
    const float* __restrict__ Wv, const float* __restrict__ Wo,
    unsigned short* __restrict__ w16)
{
    const int t = threadIdx.x;
    const int which = blockIdx.y;
    const float* src = (which == 0) ? Wq : ((which == 1) ? Wk : ((which == 2) ? Wv : Wo));
    const float scale = (which == 1) ? (ATT_SCALE * L2E) : 1.0f;
    const int base = (blockIdx.x * 256 + t) * 16;
    #pragma unroll
    for (int i = 0; i < 4; ++i) {
        const int idx = base + i * 4;
        float4 v = *(const float4*)&src[idx];
        union { unsigned short h[4]; uint2 u; } pk;
        pk.h[0] = f2bf(v.x * scale); pk.h[1] = f2bf(v.y * scale);
        pk.h[2] = f2bf(v.z * scale); pk.h[3] = f2bf(v.w * scale);
        *(uint2*)&w16[(size_t)which * 65536 + idx] = pk.u;
    }
}

// ---------------------------------------------------------------------------
// QKV GEMM with INTEGRATED x transpose (R7 grid) + COALESCED K/V STORES
// (R9 epilogue).  Block = (b,h,token-half), 16 waves.  MFMA loop identical
// to R7 -> bit-identical q/k/v.  Epilogue: K and V assembled in the dead
// x-staging LDS (scatter hits banks, not cachelines), then copied out as
// dense uint4 stores into their 32 KB contiguous global regions -- removes
// the partial-cacheline RMW that R8's counters exposed (WRITE 84 MB vs 48
// payload).  Q stores already cover full 64 B lines per row; unchanged.
// ---------------------------------------------------------------------------
__global__ __launch_bounds__(1024, 4) void qkv_kernel(
    const float* __restrict__ x,              // (b,c,n) f32
    const unsigned short* __restrict__ w16,   // wq|wk|wv|wo (wk pre-scaled)
    unsigned short* __restrict__ q16,         // (b,n,h,32)
    unsigned short* __restrict__ k16,         // (b,h, 64 frag, 512)
    unsigned short* __restrict__ v16)         // (b,h, 64 frag, 512)
{
    __shared__ __align__(16) unsigned char smem[32 * XSTR * 4];   // 64.25 KB
    float* lx = (float*)smem;                                     // loop phase
    unsigned short* bufK = (unsigned short*)smem;                 // 32 KB epilogue
    unsigned short* bufV = (unsigned short*)(smem + 32768);       // 32 KB epilogue

    const int id   = blockIdx.x;                    // 0..255
    const int bh_i = (id & 7) * 16 + (id >> 4);
    const int tokhalf = (id >> 3) & 1;
    const int b = bh_i >> 3, h = bh_i & 7;

    const int t = threadIdx.x, wid = t >> 6, lane = t & 63;
    const int g = lane >> 4, ln = lane & 15;
    const int trl = wid * 32;                       // wave's 32 tokens (block-local)
    const int tok0 = tokhalf * 512;

    const float* xb = x + (size_t)b * CDIM * NTOK;
    const unsigned short* wqh = w16 + (size_t)(h * 32) * CDIM;
    const unsigned short* wkh = w16 + 65536 + (size_t)(h * 32) * CDIM;
    const unsigned short* wvh = w16 + 2 * 65536 + (size_t)(h * 32) * CDIM;

    f32x4 aq[2][2], ak[2][2], av[2][2];
    #pragma unroll
    for (int m = 0; m < 2; ++m)
        #pragma unroll
        for (int n = 0; n < 2; ++n) {
            aq[m][n] = (f32x4){0.f, 0.f, 0.f, 0.f};
            ak[m][n] = (f32x4){0.f, 0.f, 0.f, 0.f};
            av[n][m] = (f32x4){0.f, 0.f, 0.f, 0.f};
        }

    const int scc = t >> 7;          // staging c-row within octet (0..7)
    const int sn0 = (t & 127) * 4;   // staging token offset (one float4)

    for (int kt = 0; kt < CDIM; kt += 32) {
        if (kt) __syncthreads();     // prior chunk's reads done before overwrite
        // ---- stage: 32 c-rows x 512 tokens, f32 (coalesced 2KB per 128 thr) ----
        #pragma unroll
        for (int p = 0; p < 4; ++p) {
            const int cc = scc + 8 * p;
            const float4 v = *(const float4*)&xb[(size_t)(kt + cc) * NTOK + tok0 + sn0];
            *(float2*)&lx[cc * XSTR + sn0]     = make_float2(v.x, v.y);
            *(float2*)&lx[cc * XSTR + sn0 + 2] = make_float2(v.z, v.w);
        }
        __syncthreads();
        // ---- fragments: column reads (8 c per token), cvt_pk -> bf16 ----
        bf16x8 xf[2];
        #pragma unroll
        for (int m = 0; m < 2; ++m) {
            const float* col = &lx[(size_t)(g * 8) * XSTR + trl + m * 16 + ln];
            union { unsigned u4[4]; bf16x8 v; } pk;
            #pragma unroll
            for (int p = 0; p < 4; ++p)
                pk.u4[p] = cvt_pk_bf16(col[(2 * p) * XSTR], col[(2 * p + 1) * XSTR]);
            xf[m] = pk.v;
        }
        bf16x8 wqf[2], wkf[2], wvf[2];
        #pragma unroll
        for (int n = 0; n < 2; ++n) {
            wqf[n] = *(const bf16x8*)&wqh[(size_t)(n * 16 + ln) * CDIM + kt + g * 8];
            wkf[n] = *(const bf16x8*)&wkh[(size_t)(n * 16 + ln) * CDIM + kt + g * 8];
            wvf[n] = *(const bf16x8*)&wvh[(size_t)(n * 16 + ln) * CDIM + kt + g * 8];
        }
        #pragma unroll
        for (int m = 0; m < 2; ++m)
            #pragma unroll
            for (int n = 0; n < 2; ++n) {
                aq[m][n] = __builtin_amdgcn_mfma_f32_16x16x32_bf16(xf[m], wqf[n], aq[m][n], 0, 0, 0);
                ak[m][n] = __builtin_amdgcn_mfma_f32_16x16x32_bf16(xf[m], wkf[n], ak[m][n], 0, 0, 0);
                av[n][m] = __builtin_amdgcn_mfma_f32_16x16x32_bf16(wvf[n], xf[m], av[n][m], 0, 0, 0);
            }
    }

    __syncthreads();   // all waves done reading lx -> safe to overlay bufK/bufV

    const int tr = tok0 + trl;
    // ---- Q store, row-major (unchanged: each row's 64B line fully covered) ----
    #pragma unroll
    for (int m = 0; m < 2; ++m)
        #pragma unroll
        for (int n = 0; n < 2; ++n)
            #pragma unroll
            for (int r = 0; r < 4; ++r)
                q16[((size_t)(b * NTOK + tr + m * 16 + g * 4 + r) * 8 + h) * 32 + n * 16 + ln] =
                    f2bf(aq[m][n][r]);

    // ---- assemble K into bufK (local frag = wid*2 + (g&1)) ----
    #pragma unroll
    for (int m = 0; m < 2; ++m)
        #pragma unroll
        for (int n = 0; n < 2; ++n) {
            const int lhi = (2 * n + (ln >> 3)) * 16 + (m * 2 + (g >> 1)) * 4;
            unsigned short* dst = &bufK[(wid * 2 + (g & 1)) * 512 + (ln & 7)];
            #pragma unroll
            for (int r = 0; r < 4; ++r)
                dst[(lhi + r) * 8] = f2bf(ak[m][n][r]);
        }
    // ---- assemble V into bufV (local frag = wid*2 + n) ----
    #pragma unroll
    for (int n = 0; n < 2; ++n) {
        unsigned short* dst = &bufV[(wid * 2 + n) * 512 + (ln & 7)];
        #pragma unroll
        for (int m = 0; m < 2; ++m) {
            const int lnb = (m * 2 + (ln >> 3)) * 16 + g * 4;
            #pragma unroll
            for (int r = 0; r < 4; ++r)
                dst[(lnb + r) * 8] = f2bf(av[n][m][r]);
        }
    }
    __syncthreads();

    // ---- coalesced copy out: 32 KB each, dense uint4 (2048 per buffer) ----
    unsigned short* kb16 = k16 + (size_t)(b * 8 + h) * 32768 + tokhalf * 16384;
    unsigned short* vb16 = v16 + (size_t)(b * 8 + h) * 32768 + tokhalf * 16384;
    #pragma unroll
    for (int uu = 0; uu < 2; ++uu) {
        const int u = t + uu * 1024;
        *(uint4*)&kb16[u * 8] = *(const uint4*)&bufK[u * 8];
        *(uint4*)&vb16[u * 8] = *(const uint4*)&bufV[u * 8];
    }
}

// ---------------------------------------------------------------------------
// Flash attention.  Block = (b, h, query-half): 1024 thr/16 waves.
// Proven R6/R7 schedule (unchanged).
// Structural note: 152.6 KB LDS pins 1 block/CU (4 waves/SIMD).  2 blocks/CU
// needs <=80 KB (K/V alone is 128 KB) AND <=64 VGPR (loop needs ~100) --
// both infeasible (R10: forced 8 waves/SIMD -> 776 MB scratch spill).
// ---------------------------------------------------------------------------
__global__ __launch_bounds__(1024, 4) void attn_kernel(
    const unsigned short* __restrict__ q16,   // (b,n,h,32)
    const unsigned short* __restrict__ k16,   // (b,h,64,512) frag-major
    const unsigned short* __restrict__ v16,   // (b,h,64,512) frag-major
    const float* __restrict__ rel_bias,       // (h, 3969)
    unsigned short* __restrict__ ao16)        // (b, n, 256)
{
    __shared__ __align__(16) unsigned char smem[65536 + 65536 + BSTR * 4 * 4];
    unsigned short* k_s   = (unsigned short*)smem;             // 64 frags x 512 shorts
    unsigned short* v_s   = (unsigned short*)(smem + 65536);   // 64 frags x 512 shorts
    float*          bias4 = (float*)(smem + 131072);           // [4][BSTR]

    const int id   = blockIdx.x;                    // 0..255
    const int bh_i = (id & 7) * 16 + (id >> 4);     // XCD x owns bh [16x,16x+16)
    const int half = (id >> 3) & 1;
    const int b = bh_i >> 3, h = bh_i & 7;

    const int t = threadIdx.x, wid = t >> 6, lane = t & 63;
    const int g = lane >> 4, ln = lane & 15;
    const int qb = half * 512 + wid * 32;           // wave's 32 queries

    const unsigned short* kbh = k16 + (size_t)(b * 8 + h) * 32768;
    const unsigned short* vbh = v16 + (size_t)(b * 8 + h) * 32768;

    // ---- stage K/V fragments: global -> reg (issue early) ----
    bf16x8 sk[4], sv[4];
    #pragma unroll
    for (int j = 0; j < 4; ++j) {
        const int f = wid * 4 + j;
        sk[j] = *(const bf16x8*)&kbh[(size_t)f * 512 + lane * 8];
        sv[j] = *(const bf16x8*)&vbh[(size_t)f * 512 + lane * 8];
    }
    // ---- Q fragments ----
    const bf16x8 aq0 = *(const bf16x8*)&q16[((size_t)(b * NTOK + qb + ln) * 8 + h) * 32 + g * 8];
    const bf16x8 aq1 = *(const bf16x8*)&q16[((size_t)(b * NTOK + qb + 16 + ln) * 8 + h) * 32 + g * 8];

    // ---- bias*log2e -> 4 shift-aligned copies (overlaps the loads above) ----
    {
        const int START = 544 - 512 * half;         // 4-aligned window base
        const float* brow = rel_bias + (size_t)h * 3969;
        for (int i = t; i < 1540; i += 1024) {
            #pragma unroll
            for (int a = 0; a < 4; ++a)
                bias4[a * BSTR + i] = brow[START + a + i] * L2E;
        }
    }

    // ---- commit staged frags to LDS (linear in lane = conflict-free) ----
    #pragma unroll
    for (int j = 0; j < 4; ++j) {
        const int f = wid * 4 + j;
        *(bf16x8*)&k_s[(size_t)f * 512 + lane * 8] = sk[j];
        *(bf16x8*)&v_s[(size_t)f * 512 + lane * 8] = sv[j];
    }

    __syncthreads();   // K, V, bias all LDS-resident

    // ---- Stage 2: attention main loop (R1 schedule, verbatim) ----
    const int boffL = 512 + 8 * g - wid * 32 - ln;   // local bias offset
    const int ba = boffL & 3;
    const float* bb = &bias4[ba * BSTR + (boffL - ba)];
    const unsigned short* kfp = k_s + lane * 8;      // frag stride 512 shorts
    const unsigned short* vfp = v_s + lane * 8;

    f32x4 o00 = {0.f,0.f,0.f,0.f}, o01 = {0.f,0.f,0.f,0.f};
    f32x4 o10 = {0.f,0.f,0.f,0.f}, o11 = {0.f,0.f,0.f,0.f};
    f32x4 ls0 = {0.f,0.f,0.f,0.f}, ls1 = {0.f,0.f,0.f,0.f};
    const short one_bf = (short)0x3F80;
    const bf16x8 ones = {one_bf,one_bf,one_bf,one_bf,one_bf,one_bf,one_bf,one_bf};

    // prologue: iter-0 K fragments + bias C-operands
    bf16x8 kf0 = *(const bf16x8*)&kfp[0];
    bf16x8 kf1 = *(const bf16x8*)&kfp[512];
    f32x4  cA0 = *(const f32x4*)&bb[0];
    f32x4  cA1 = *(const f32x4*)&bb[4];
    f32x4  cB0 = *(const f32x4*)&bb[-16];
    f32x4  cB1 = *(const f32x4*)&bb[-12];

    for (int kb = 0; kb < NTOK; kb += 32) {
        const int fi = (kb >> 5) * 2;
        // V for THIS iter: consumed only after S-MFMA + exp chain -> self-hiding.
        const bf16x8 vA0 = *(const bf16x8*)&vfp[fi * 512];
        const bf16x8 vA1 = *(const bf16x8*)&vfp[(fi + 1) * 512];
        // prefetch NEXT iter's K + bias (wrap keeps addresses in-bounds).
        const int kn = (kb + 32) & (NTOK - 1);
        const int fn = (kn >> 5) * 2;
        const bf16x8 nk0 = *(const bf16x8*)&kfp[fn * 512];
        const bf16x8 nk1 = *(const bf16x8*)&kfp[(fn + 1) * 512];
        const f32x4  nA0 = *(const f32x4*)&bb[kn];
        const f32x4  nA1 = *(const f32x4*)&bb[kn + 4];
        const f32x4  nB0 = *(const f32x4*)&bb[kn - 16];
        const f32x4  nB1 = *(const f32x4*)&bb[kn - 12];

        __builtin_amdgcn_s_setprio(1);
        f32x4 s00 = __builtin_amdgcn_mfma_f32_16x16x32_bf16(kf0, aq0, cA0, 0, 0, 0);
        f32x4 s01 = __builtin_amdgcn_mfma_f32_16x16x32_bf16(kf1, aq0, cA1, 0, 0, 0);
        f32x4 s10 = __builtin_amdgcn_mfma_f32_16x16x32_bf16(kf0, aq1, cB0, 0, 0, 0);
        f32x4 s11 = __builtin_amdgcn_mfma_f32_16x16x32_bf16(kf1, aq1, cB1, 0, 0, 0);
        __builtin_amdgcn_s_setprio(0);

        // Pack P: shorts [e(s0[0..3]) | e(s1[0..3])] = keys kb+8g+0..7 in order.
        union { unsigned u4[4]; bf16x8 v; } ap0, ap1;
        ap0.u4[0] = cvt_pk_bf16(__builtin_amdgcn_exp2f(s00[0]), __builtin_amdgcn_exp2f(s00[1]));
        ap0.u4[1] = cvt_pk_bf16(__builtin_amdgcn_exp2f(s00[2]), __builtin_amdgcn_exp2f(s00[3]));
        ap0.u4[2] = cvt_pk_bf16(__builtin_amdgcn_exp2f(s01[0]), __builtin_amdgcn_exp2f(s01[1]));
        ap0.u4[3] = cvt_pk_bf16(__builtin_amdgcn_exp2f(s01[2]), __builtin_amdgcn_exp2f(s01[3]));
        ap1.u4[0] = cvt_pk_bf16(__builtin_amdgcn_exp2f(s10[0]), __builtin_amdgcn_exp2f(s10[1]));
        ap1.u4[1] = cvt_pk_bf16(__builtin_amdgcn_exp2f(s10[2]), __builtin_amdgcn_exp2f(s10[3]));
        ap1.u4[2] = cvt_pk_bf16(__builtin_amdgcn_exp2f(s11[0]), __builtin_amdgcn_exp2f(s11[1]));
        ap1.u4[3] = cvt_pk_bf16(__builtin_amdgcn_exp2f(s11[2]), __builtin_amdgcn_exp2f(s11[3]));

        __builtin_amdgcn_s_setprio(1);
        o00 = __builtin_amdgcn_mfma_f32_16x16x32_bf16(ap0.v, vA0, o00, 0, 0, 0);
        o01 = __builtin_amdgcn_mfma_f32_16x16x32_bf16(ap0.v, vA1, o01, 0, 0, 0);
        ls0 = __builtin_amdgcn_mfma_f32_16x16x32_bf16(ap0.v, ones, ls0, 0, 0, 0);
        o10 = __builtin_amdgcn_mfma_f32_16x16x32_bf16(ap1.v, vA0, o10, 0, 0, 0);
        o11 = __builtin_amdgcn_mfma_f32_16x16x32_bf16(ap1.v, vA1, o11, 0, 0, 0);
        ls1 = __builtin_amdgcn_mfma_f32_16x16x32_bf16(ap1.v, ones, ls1, 0, 0, 0);
        __builtin_amdgcn_s_setprio(0);

        kf0 = nk0; kf1 = nk1;
        cA0 = nA0; cA1 = nA1; cB0 = nB0; cB1 = nB1;
    }

    #pragma unroll
    for (int r = 0; r < 4; ++r) {
        float i0 = 1.f / ls0[r], i1 = 1.f / ls1[r];
        o00[r] *= i0; o01[r] *= i0;
        o10[r] *= i1; o11[r] *= i1;
    }

    __syncthreads();   // all waves done with k_s; overlay otr on K region
    unsigned short (*otr)[32][40] = (unsigned short(*)[32][40])smem;
    #pragma unroll
    for (int r = 0; r < 4; ++r) {
        otr[wid][g * 4 + r][ln]           = f2bf(o00[r]);
        otr[wid][g * 4 + r][16 + ln]      = f2bf(o01[r]);
        otr[wid][16 + g * 4 + r][ln]      = f2bf(o10[r]);
        otr[wid][16 + g * 4 + r][16 + ln] = f2bf(o11[r]);
    }
    // same-wave region: DS in-order, no barrier.  2 lanes/row x 16 d each.
    const int row = lane >> 1;
    const int ch  = (lane & 1) * 16;
    uint4 st0 = *(uint4*)&otr[wid][row][ch];
    uint4 st1 = *(uint4*)&otr[wid][row][ch + 8];
    unsigned short* dst = &ao16[((size_t)b * NTOK + qb + row) * CDIM + h * HDIM + ch];
    *(uint4*)dst     = st0;
    *(uint4*)&dst[8] = st1;
}

// ---------------------------------------------------------------------------
// Output projection: 64c x 128p per block, wave = 2 c-frags x 4 p-frags.
// XCD-swizzled flat grid 512.  (Unchanged.)
// ---------------------------------------------------------------------------
__global__ __launch_bounds__(256) void outproj_kernel(
    const unsigned short* __restrict__ ao16,  // (b,n,256)
    const unsigned short* __restrict__ wo16,  // (256,256)
    const float* __restrict__ bo,
    float* __restrict__ y)                    // (b,256,n)
{
    const int id   = blockIdx.x;              // 0..511
    const int b    = (id & 7) * 2 + ((id >> 3) & 1);
    const int rest = id >> 4;                 // 0..31
    const int ct   = (rest & 3) * 64;
    const int pt   = (rest >> 2) * 128;
    const int t = threadIdx.x, wid = t >> 6, lane = t & 63;
    const int g = lane >> 4, ln = lane & 15;
    const int cb2 = ct + (wid & 1) * 32;
    const int pb  = pt + (wid >> 1) * 64;
    const unsigned short* ab = ao16 + (size_t)b * NTOK * CDIM;

    f32x4 acc[2][4];
    #pragma unroll
    for (int n = 0; n < 2; ++n)
        #pragma unroll
        for (int m = 0; m < 4; ++m) acc[n][m] = (f32x4){0.f, 0.f, 0.f, 0.f};

    #pragma unroll
    for (int kt = 0; kt < CDIM; kt += 32) {
        bf16x8 aw[2], bx[4];
        #pragma unroll
        for (int n = 0; n < 2; ++n)
            aw[n] = *(const bf16x8*)&wo16[(size_t)(cb2 + n * 16 + ln) * CDIM + kt + g * 8];
        #pragma unroll
        for (int m = 0; m < 4; ++m)
            bx[m] = *(const bf16x8*)&ab[(size_t)(pb + m * 16 + ln) * CDIM + kt + g * 8];
        #pragma unroll
        for (int n = 0; n < 2; ++n)
            #pragma unroll
            for (int m = 0; m < 4; ++m)
                acc[n][m] = __builtin_amdgcn_mfma_f32_16x16x32_bf16(aw[n], bx[m], acc[n][m], 0, 0, 0);
    }
    #pragma unroll
    for (int n = 0; n < 2; ++n)
        #pragma unroll
        for (int r = 0; r < 4; ++r) {
            const int c = cb2 + n * 16 + g * 4 + r;
            const float bias = bo[c];
            #pragma unroll
            for (int m = 0; m < 4; ++m)
                y[((size_t)b * CDIM + c) * NTOK + pb + m * 16 + ln] = acc[n][m][r] + bias;
        }
}

// ---------------------------------------------------------------------------
extern "C" void kernel_launch(void* const* d_in, const int* in_sizes, int n_in,
                              void* d_out, int out_size, void* d_ws, size_t ws_size,
                              hipStream_t stream) {
    const float* x        = (const float*)d_in[0];
    const float* Wq       = (const float*)d_in[1];
    const float* Wk       = (const float*)d_in[2];
    const float* Wv       = (const float*)d_in[3];
    const float* Wo       = (const float*)d_in[4];
    const float* bo       = (const float*)d_in[5];
    const float* rel_bias = (const float*)d_in[6];
    (void)in_sizes; (void)n_in; (void)ws_size; (void)out_size;
    // d_in[7] = rel_idx: unused — bias index computed analytically (j - p + 1056)

    unsigned short* ws16 = (unsigned short*)d_ws;
    unsigned short* w16  = ws16;                                   // 512 KB
    unsigned short* q16  = ws16 + 4 * 65536;                       // 8 MB
    unsigned short* k16  = q16 + (size_t)4 * 1024 * 1024;          // 8 MB
    unsigned short* v16  = k16 + (size_t)4 * 1024 * 1024;          // 8 MB
    unsigned short* ao16 = v16 + (size_t)4 * 1024 * 1024;          // 8 MB
    float* y = (float*)d_out;

    prepw_kernel<<<dim3(16, 4), 256, 0, stream>>>(Wq, Wk, Wv, Wo, w16);
    qkv_kernel<<<256, 1024, 0, stream>>>(x, w16, q16, k16, v16);
    attn_kernel<<<256, 1024, 0, stream>>>(q16, k16, v16, rel_bias, ao16);
    outproj_kernel<<<512, 256, 0, stream>>>(ao16, w16 + 3 * 65536, bo, y);
}